// Round 7
// baseline (261.496 us; speedup 1.0000x reference)
//
#include <hip/hip_runtime.h>
#include <hip/hip_cooperative_groups.h>

namespace cg = cooperative_groups;

// Problem constants (B=1, D=128, H=64, W=96, 4 levels, radius 4)
#define D 128
#define H0 64
#define W0 96
#define HW0 6144
#define INV_SQRT_D 0.08838834764831843f

// Workspace layout (float offsets)
#define OFF_F1T0 0
#define OFF_F2T0 786432
#define OFF_F1T1 1572864
#define OFF_F2T1 1769472
#define OFF_F1T2 1966080
#define OFF_F2T2 2015232
#define OFF_F1T3 2064384
#define OFF_F2T3 2076672
#define OFF_C1   2088960
#define OFF_C2   2092032
#define OFF_C3   2092800
#define OFF_G    2092992   // 8160*100 floats

// Output offsets (floats)
#define OUT_L0 0
#define OUT_L1 497664
#define OUT_L2 622080
#define OUT_L3 653184

__device__ __forceinline__ void gp_to_level(int gp, int& level, int& p) {
    if (gp < 6144)      { level = 0; p = gp; }
    else if (gp < 7680) { level = 1; p = gp - 6144; }
    else if (gp < 8064) { level = 2; p = gp - 7680; }
    else                { level = 3; p = gp - 8064; }
}

// ---------------------------------------------------------------------------
// Fused cooperative kernel: Phase A prep -> grid.sync -> Phase B dots ->
// grid.sync -> Phase C combine. Grid 512 x 256 (co-resident: 26.4KB LDS ->
// 6 blocks/CU capacity, need 2).
// ---------------------------------------------------------------------------
__global__ __launch_bounds__(256) void k_fused(const float* __restrict__ f1,
                                               const float* __restrict__ f2,
                                               const float* __restrict__ coords,
                                               float* __restrict__ ws,
                                               float* __restrict__ out) {
    cg::grid_group grid = cg::this_grid();
    __shared__ float smem[6592];   // phase A: T[64*69]; phase C: Gs[64*101]+cxs+cys

    const int b = blockIdx.x;
    const int t = threadIdx.x;

    // ---------------- Phase A: transpose+pools (jobs 0..383) + coords (384..399)
    if (b < 384) {
        float* T = smem;                  // [pixel_local][d_local], stride 69
        const int m = b / 192;
        const int rb = b - m * 192;
        const int tix = rb >> 1;          // 0..95
        const int dh = rb & 1;            // d half
        const int tr = tix / 12, tc = tix - (tix / 12) * 12;
        const float* in = (m ? f2 : f1) + dh * 64 * HW0;

        const int l = t & 63;
        const int gbase = (tr * 8 + (l >> 3)) * W0 + tc * 8 + (l & 7);
#pragma unroll 4
        for (int pass = 0; pass < 16; ++pass) {
            int d = pass * 4 + (t >> 6);
            T[l * 69 + d] = in[d * HW0 + gbase];
        }
        __syncthreads();

        float* o0 = ws + (m ? OFF_F2T0 : OFF_F1T0) + dh * 64;
#pragma unroll 4
        for (int pass = 0; pass < 16; ++pass) {
            int e = t + pass * 256;
            int pl = e >> 6, c = e & 63;
            int gp = (tr * 8 + (pl >> 3)) * W0 + tc * 8 + (pl & 7);
            o0[gp * D + c] = T[pl * 69 + c];
        }
        float* o1 = ws + (m ? OFF_F2T1 : OFF_F1T1) + dh * 64;
#pragma unroll
        for (int pass = 0; pass < 4; ++pass) {
            int e = t + pass * 256;
            int d = e & 63, p1 = e >> 6;            // p1 0..15
            int i1 = p1 >> 2, j1 = p1 & 3;
            int l00 = (i1 * 2) * 8 + j1 * 2;
            float v = T[l00 * 69 + d] + T[(l00 + 1) * 69 + d]
                    + T[(l00 + 8) * 69 + d] + T[(l00 + 9) * 69 + d];
            o1[((tr * 4 + i1) * 48 + tc * 4 + j1) * D + d] = 0.25f * v;
        }
        float* o2 = ws + (m ? OFF_F2T2 : OFF_F1T2) + dh * 64;
        {
            int d = t & 63, p2 = t >> 6;            // p2 0..3
            int i2 = p2 >> 1, j2 = p2 & 1;
            float acc = 0.0f;
#pragma unroll
            for (int a = 0; a < 4; ++a)
#pragma unroll
                for (int c2 = 0; c2 < 4; ++c2)
                    acc += T[((i2 * 4 + a) * 8 + j2 * 4 + c2) * 69 + d];
            o2[((tr * 2 + i2) * 24 + tc * 2 + j2) * D + d] = acc * 0.0625f;
        }
        float* o3 = ws + (m ? OFF_F2T3 : OFF_F1T3) + dh * 64;
        if (t < 64) {
            float acc = 0.0f;
            for (int l2 = 0; l2 < 64; ++l2) acc += T[l2 * 69 + t];
            o3[(tr * 12 + tc) * D + t] = acc * 0.015625f;
        }
    } else if (b < 400) {
        // coords resize (jax.image.resize linear, antialias=True) + /2^l
        int idx = (b - 384) * 256 + t;
        if (idx < 4032) {
            int level, r = idx;
            if (r < 3072) { level = 1; }
            else if (r < 3840) { level = 2; r -= 3072; }
            else { level = 3; r -= 3840; }
            const int Hl = H0 >> level, Wl = W0 >> level;
            const float ff = (float)(1 << level);
            const int npix = Hl * Wl;
            const int ch = r / npix;
            const int rem = r - ch * npix;
            const int ho = rem / Wl, wo = rem - (rem / Wl) * Wl;

            const float sfy = (ho + 0.5f) * ff - 0.5f;
            const float sfx = (wo + 0.5f) * ff - 0.5f;
            int ylo = max(0, (int)ceilf(sfy - ff));
            int yhi = min(H0 - 1, (int)floorf(sfy + ff));
            int xlo = max(0, (int)ceilf(sfx - ff));
            int xhi = min(W0 - 1, (int)floorf(sfx + ff));

            float acc = 0.0f, wsum_y = 0.0f, wsum_x = 0.0f;
            for (int iy = ylo; iy <= yhi; ++iy) {
                float wy = fmaxf(1.0f - fabsf(sfy - (float)iy) / ff, 0.0f);
                wsum_y += wy;
                float rowacc = 0.0f;
                for (int ix = xlo; ix <= xhi; ++ix) {
                    float wx = fmaxf(1.0f - fabsf(sfx - (float)ix) / ff, 0.0f);
                    if (iy == ylo) wsum_x += wx;
                    rowacc += wx * coords[ch * HW0 + iy * W0 + ix];
                }
                acc += wy * rowacc;
            }
            float val = acc / (wsum_y * wsum_x) / ff;
            const int coffs[4] = {0, OFF_C1, OFF_C2, OFF_C3};
            ws[coffs[level] + ch * npix + ho * Wl + wo] = val;
        }
    }

    grid.sync();

    // ---------------- Phase B: grid dots (2040 jobs, interleaved d-slicing)
    {
        const int ln = t & 63;
        const int oct = ln >> 3;
        const int sub = ln & 7;
        for (int job = b; job < 2040; job += 512) {
            const int gp = job * 4 + (t >> 6);
            int level, p;
            gp_to_level(gp, level, p);
            const int Hl = H0 >> level, Wl = W0 >> level;
            const int npix = Hl * Wl;

            const int f1offs[4] = {OFF_F1T0, OFF_F1T1, OFF_F1T2, OFF_F1T3};
            const int f2offs[4] = {OFF_F2T0, OFF_F2T1, OFF_F2T2, OFF_F2T3};
            const int coffs[4]  = {0, OFF_C1, OFF_C2, OFF_C3};

            const float* f2t = ws + f2offs[level];
            const float* cp = (level == 0) ? coords : (ws + coffs[level]);

            const float* f1p = ws + f1offs[level] + p * D + sub * 4;
            const float4 a0 = *(const float4*)(f1p + 0);
            const float4 a1 = *(const float4*)(f1p + 32);
            const float4 a2 = *(const float4*)(f1p + 64);
            const float4 a3 = *(const float4*)(f1p + 96);

            const float cx = cp[p];
            const float cy = cp[npix + p];
            const int fx = (int)floorf(cx), fy = (int)floorf(cy);
            float* Gout = ws + OFF_G + gp * 100;

#pragma unroll 2
            for (int i = 0; i < 13; ++i) {
                int g = i * 8 + oct;
                int gc = min(g, 99);
                int gy = gc / 10;
                int gx = gc - gy * 10;
                int iy = min(max(fy - 4 + gy, 0), Hl - 1);
                int ix = min(max(fx - 4 + gx, 0), Wl - 1);
                const float* row = f2t + (iy * Wl + ix) * D + sub * 4;
                const float4 v0 = *(const float4*)(row + 0);
                const float4 v1 = *(const float4*)(row + 32);
                const float4 v2 = *(const float4*)(row + 64);
                const float4 v3 = *(const float4*)(row + 96);
                float s = (a0.x * v0.x + a0.y * v0.y) + (a0.z * v0.z + a0.w * v0.w)
                        + (a1.x * v1.x + a1.y * v1.y) + (a1.z * v1.z + a1.w * v1.w)
                        + (a2.x * v2.x + a2.y * v2.y) + (a2.z * v2.z + a2.w * v2.w)
                        + (a3.x * v3.x + a3.y * v3.y) + (a3.z * v3.z + a3.w * v3.w);
                s += __shfl_xor(s, 1);
                s += __shfl_xor(s, 2);
                s += __shfl_xor(s, 4);
                if (sub == 0 && g < 100) Gout[g] = s;
            }
        }
    }

    grid.sync();

    // ---------------- Phase C: combine (512 jobs: 128 pixel-groups x 4 k-quarters)
    {
        float* Gs  = smem;          // 64*101
        float* cxs = smem + 6464;   // 64
        float* cys = smem + 6528;   // 64
        const int pg = b >> 2;      // 0..127
        const int kq = b & 3;
        const int gp0 = pg * 64;
        const int coffs[4]  = {0, OFF_C1, OFF_C2, OFF_C3};
        const int outoffs[4] = {OUT_L0, OUT_L1, OUT_L2, OUT_L3};

        for (int it = 0; it < 25; ++it) {
            int e = t + it * 256;                 // 0..6399
            int px = e / 100, g = e - px * 100;
            if (px < 64 && gp0 + px < 8160)
                Gs[px * 101 + g] = ws[OFF_G + (gp0 + px) * 100 + g];
        }
        if (t < 64 && gp0 + t < 8160) {
            int level, p;
            gp_to_level(gp0 + t, level, p);
            const float* cp = (level == 0) ? coords : (ws + coffs[level]);
            int npix = (H0 >> level) * (W0 >> level);
            cxs[t] = cp[p];
            cys[t] = cp[npix + p];
        }
        __syncthreads();

        const int w = t >> 6;
        const int px = t & 63;
        const int gp = gp0 + px;
        if (gp < 8160) {
            int level, p;
            gp_to_level(gp, level, p);
            const int Hl = H0 >> level, Wl = W0 >> level;
            const int npix = Hl * Wl;
            float* outp = out + outoffs[level] + p;
            const float cx = cxs[px], cy = cys[px];
            const float Wm1 = (float)(Wl - 1), Hm1 = (float)(Hl - 1);
            const float* Gp = &Gs[px * 101];

            for (int k = kq * 4 + w; k < 81; k += 16) {
                int dxi = k / 9, dyi = k - (k / 9) * 9;
                float x = fminf(fmaxf(cx + (float)(dxi - 4), 0.0f), Wm1);
                float y = fminf(fmaxf(cy + (float)(dyi - 4), 0.0f), Hm1);
                float wx1 = x - floorf(x), wx0 = 1.0f - wx1;
                float wy1 = y - floorf(y), wy0 = 1.0f - wy1;
                int g00 = dyi * 10 + dxi;
                float v = wx0 * wy0 * Gp[g00]      + wx1 * wy0 * Gp[g00 + 1]
                        + wx0 * wy1 * Gp[g00 + 10] + wx1 * wy1 * Gp[g00 + 11];
                outp[k * npix] = v * INV_SQRT_D;
            }
        }
    }
}

// ---------------------------------------------------------------------------
extern "C" void kernel_launch(void* const* d_in, const int* in_sizes, int n_in,
                              void* d_out, int out_size, void* d_ws, size_t ws_size,
                              hipStream_t stream) {
    const float* fmap1  = (const float*)d_in[0];
    const float* fmap2  = (const float*)d_in[1];
    const float* coords = (const float*)d_in[2];
    float* out = (float*)d_out;
    float* ws = (float*)d_ws;

    void* args[] = { (void*)&fmap1, (void*)&fmap2, (void*)&coords,
                     (void*)&ws, (void*)&out };
    hipLaunchCooperativeKernel((const void*)k_fused, dim3(512), dim3(256),
                               args, 0, stream);
}

// Round 8
// 98.689 us; speedup vs baseline: 2.6497x; 2.6497x over previous
//
#include <hip/hip_runtime.h>
#include <hip/hip_fp16.h>

// Problem constants (B=1, D=128, H=64, W=96, 4 levels, radius 4)
#define D 128
#define H0 64
#define W0 96
#define HW0 6144
#define INV_SQRT_D 0.08838834764831843f

// Half-precision feature-map workspace (offsets in _Float16 units)
#define H_F1T0 0
#define H_F1T1 786432
#define H_F1T2 983040
#define H_F1T3 1032192
#define H_F2T0 1048576
#define H_F2T1 1835008
#define H_F2T2 2031616
#define H_F2T3 2080768
// Coords (fp32, offsets in float units; starts at byte 8.39MB)
#define OFF_C1 2097152
#define OFF_C2 2100224
#define OFF_C3 2100992

// Output offsets (floats)
#define OUT_L0 0
#define OUT_L1 497664
#define OUT_L2 622080
#define OUT_L3 653184

typedef _Float16 h2 __attribute__((ext_vector_type(2)));
union F4H { float4 f; h2 h[4]; };

__device__ __forceinline__ float dot2f(h2 a, h2 b, float c) {
#if __has_builtin(__builtin_amdgcn_fdot2)
    return __builtin_amdgcn_fdot2(a, b, c, false);
#else
    return c + (float)a.x * (float)b.x + (float)a.y * (float)b.y;
#endif
}

__device__ __forceinline__ void gp_to_level(int gp, int& level, int& p) {
    if (gp < 6144)      { level = 0; p = gp; }
    else if (gp < 7680) { level = 1; p = gp - 6144; }
    else if (gp < 8064) { level = 2; p = gp - 7680; }
    else                { level = 3; p = gp - 8064; }
}

// ---------------------------------------------------------------------------
// K1: fused tile transpose + pools (blocks 0..383, d-split), fp16 outputs,
// + coords resize (blocks 384..399).
// ---------------------------------------------------------------------------
__global__ __launch_bounds__(256) void k_prep(const float* __restrict__ f1,
                                              const float* __restrict__ f2,
                                              const float* __restrict__ coords,
                                              float* __restrict__ ws) {
    const int b = blockIdx.x;
    const int t = threadIdx.x;
    _Float16* wh = (_Float16*)ws;
    if (b < 384) {
        __shared__ float T[64 * 69];    // [pixel_local][d_local], stride 69
        const int m = b / 192;
        const int rb = b - m * 192;
        const int tix = rb >> 1;        // 0..95
        const int dh = rb & 1;          // d half
        const int tr = tix / 12, tc = tix - (tix / 12) * 12;
        const float* in = (m ? f2 : f1) + dh * 64 * HW0;

        const int l = t & 63;
        const int gbase = (tr * 8 + (l >> 3)) * W0 + tc * 8 + (l & 7);
#pragma unroll 4
        for (int pass = 0; pass < 16; ++pass) {
            int d = pass * 4 + (t >> 6);
            T[l * 69 + d] = in[d * HW0 + gbase];
        }
        __syncthreads();

        _Float16* o0 = wh + (m ? H_F2T0 : H_F1T0) + dh * 64;
#pragma unroll 4
        for (int pass = 0; pass < 16; ++pass) {
            int e = t + pass * 256;
            int pl = e >> 6, c = e & 63;
            int gp = (tr * 8 + (pl >> 3)) * W0 + tc * 8 + (pl & 7);
            o0[gp * D + c] = (_Float16)T[pl * 69 + c];
        }
        _Float16* o1 = wh + (m ? H_F2T1 : H_F1T1) + dh * 64;
#pragma unroll
        for (int pass = 0; pass < 4; ++pass) {
            int e = t + pass * 256;
            int d = e & 63, p1 = e >> 6;            // p1 0..15
            int i1 = p1 >> 2, j1 = p1 & 3;
            int l00 = (i1 * 2) * 8 + j1 * 2;
            float v = T[l00 * 69 + d] + T[(l00 + 1) * 69 + d]
                    + T[(l00 + 8) * 69 + d] + T[(l00 + 9) * 69 + d];
            o1[((tr * 4 + i1) * 48 + tc * 4 + j1) * D + d] = (_Float16)(0.25f * v);
        }
        _Float16* o2 = wh + (m ? H_F2T2 : H_F1T2) + dh * 64;
        {
            int d = t & 63, p2 = t >> 6;            // p2 0..3
            int i2 = p2 >> 1, j2 = p2 & 1;
            float acc = 0.0f;
#pragma unroll
            for (int a = 0; a < 4; ++a)
#pragma unroll
                for (int c2 = 0; c2 < 4; ++c2)
                    acc += T[((i2 * 4 + a) * 8 + j2 * 4 + c2) * 69 + d];
            o2[((tr * 2 + i2) * 24 + tc * 2 + j2) * D + d] = (_Float16)(acc * 0.0625f);
        }
        _Float16* o3 = wh + (m ? H_F2T3 : H_F1T3) + dh * 64;
        if (t < 64) {
            float acc = 0.0f;
            for (int l2 = 0; l2 < 64; ++l2) acc += T[l2 * 69 + t];
            o3[(tr * 12 + tc) * D + t] = (_Float16)(acc * 0.015625f);
        }
    } else {
        // coords resize (jax.image.resize linear, antialias=True) + /2^l
        int idx = (b - 384) * 256 + t;
        if (idx >= 4032) return;
        int level, r = idx;
        if (r < 3072) { level = 1; }
        else if (r < 3840) { level = 2; r -= 3072; }
        else { level = 3; r -= 3840; }
        const int Hl = H0 >> level, Wl = W0 >> level;
        const float ff = (float)(1 << level);
        const int npix = Hl * Wl;
        const int ch = r / npix;
        const int rem = r - ch * npix;
        const int ho = rem / Wl, wo = rem - (rem / Wl) * Wl;

        const float sfy = (ho + 0.5f) * ff - 0.5f;
        const float sfx = (wo + 0.5f) * ff - 0.5f;
        int ylo = max(0, (int)ceilf(sfy - ff));
        int yhi = min(H0 - 1, (int)floorf(sfy + ff));
        int xlo = max(0, (int)ceilf(sfx - ff));
        int xhi = min(W0 - 1, (int)floorf(sfx + ff));

        float acc = 0.0f, wsum_y = 0.0f, wsum_x = 0.0f;
        for (int iy = ylo; iy <= yhi; ++iy) {
            float wy = fmaxf(1.0f - fabsf(sfy - (float)iy) / ff, 0.0f);
            wsum_y += wy;
            float rowacc = 0.0f;
            for (int ix = xlo; ix <= xhi; ++ix) {
                float wx = fmaxf(1.0f - fabsf(sfx - (float)ix) / ff, 0.0f);
                if (iy == ylo) wsum_x += wx;
                rowacc += wx * coords[ch * HW0 + iy * W0 + ix];
            }
            acc += wy * rowacc;
        }
        float val = acc / (wsum_y * wsum_x) / ff;
        const int coffs[4] = {0, OFF_C1, OFF_C2, OFF_C3};
        ws[coffs[level] + ch * npix + ho * Wl + wo] = val;
    }
}

// ---------------------------------------------------------------------------
// K2: fused dots+combine. Block = 1024 thr = 16 waves = 16 consecutive
// pixels (one per wave; 8160 waves total -> full occupancy). Dots: 8-lane
// interleaved fp16 slices (lane sub: d = j*64 + sub*8 + 0..7), 2 fdot2x4
// loads/row; 3-shfl reduce; G -> LDS. Combine: 81x16 outputs, 16 consecutive
// p per wave-segment = 64B-aligned full-line stores.
// ---------------------------------------------------------------------------
__global__ __launch_bounds__(1024) void k_dc(const float* __restrict__ coords0,
                                             const float* __restrict__ ws,
                                             float* __restrict__ out) {
    __shared__ float Gs[16 * 101];
    __shared__ float cxs[16], cys[16];
    const _Float16* wh = (const _Float16*)ws;

    const int t = threadIdx.x;
    const int w = t >> 6;               // wave = pixel-in-block
    const int ln = t & 63;
    const int oct = ln >> 3;            // dot within iteration
    const int sub = ln & 7;             // interleaved d slice

    const int gp0 = blockIdx.x * 16;
    const int gp = gp0 + w;

    int level, p;
    gp_to_level(gp, level, p);
    const int Hl = H0 >> level, Wl = W0 >> level;
    const int npix = Hl * Wl;

    const int f1offs[4] = {H_F1T0, H_F1T1, H_F1T2, H_F1T3};
    const int f2offs[4] = {H_F2T0, H_F2T1, H_F2T2, H_F2T3};
    const int coffs[4]  = {0, OFF_C1, OFF_C2, OFF_C3};
    const int outoffs[4] = {OUT_L0, OUT_L1, OUT_L2, OUT_L3};

    const _Float16* f2t = wh + f2offs[level];
    const float* cp = (level == 0) ? coords0 : (ws + coffs[level]);

    // f1 slice: d = j*64 + sub*8 + 0..7, j=0..1 (contiguous 128B across sub)
    const _Float16* f1p = wh + f1offs[level] + p * D + sub * 8;
    F4H a0, a1;
    a0.f = *(const float4*)(f1p);
    a1.f = *(const float4*)(f1p + 64);

    const float cx = cp[p];
    const float cy = cp[npix + p];
    if (ln == 0) { cxs[w] = cx; cys[w] = cy; }
    const int fx = (int)floorf(cx), fy = (int)floorf(cy);

#pragma unroll 2
    for (int i = 0; i < 13; ++i) {
        int g = i * 8 + oct;
        int gc = min(g, 99);
        int gy = gc / 10;
        int gx = gc - gy * 10;
        int iy = min(max(fy - 4 + gy, 0), Hl - 1);
        int ix = min(max(fx - 4 + gx, 0), Wl - 1);
        const _Float16* row = f2t + (iy * Wl + ix) * D + sub * 8;
        F4H v0, v1;
        v0.f = *(const float4*)(row);
        v1.f = *(const float4*)(row + 64);
        float s = 0.0f;
        s = dot2f(a0.h[0], v0.h[0], s);
        s = dot2f(a0.h[1], v0.h[1], s);
        s = dot2f(a0.h[2], v0.h[2], s);
        s = dot2f(a0.h[3], v0.h[3], s);
        s = dot2f(a1.h[0], v1.h[0], s);
        s = dot2f(a1.h[1], v1.h[1], s);
        s = dot2f(a1.h[2], v1.h[2], s);
        s = dot2f(a1.h[3], v1.h[3], s);
        s += __shfl_xor(s, 1);
        s += __shfl_xor(s, 2);
        s += __shfl_xor(s, 4);
        if (sub == 0 && g < 100) Gs[w * 101 + g] = s;
    }
    __syncthreads();

    // ---- combine: px = t&15, k-base = t>>4 (block is level-uniform)
    {
        const int px = t & 15;
        const int kk = t >> 4;          // 0..63
        int lv0, p0;
        gp_to_level(gp0, lv0, p0);
        const int Hb = H0 >> lv0, Wb = W0 >> lv0;
        const int npb = Hb * Wb;
        float* outp = out + outoffs[lv0] + p0 + px;
        const float bx = cxs[px], by = cys[px];
        const float Wm1 = (float)(Wb - 1), Hm1 = (float)(Hb - 1);
        const float* Gp = &Gs[px * 101];

        for (int k = kk; k < 81; k += 64) {
            int dxi = k / 9, dyi = k - (k / 9) * 9;
            float x = fminf(fmaxf(bx + (float)(dxi - 4), 0.0f), Wm1);
            float y = fminf(fmaxf(by + (float)(dyi - 4), 0.0f), Hm1);
            float wx1 = x - floorf(x), wx0 = 1.0f - wx1;
            float wy1 = y - floorf(y), wy0 = 1.0f - wy1;
            int g00 = dyi * 10 + dxi;
            float v = wx0 * wy0 * Gp[g00]      + wx1 * wy0 * Gp[g00 + 1]
                    + wx0 * wy1 * Gp[g00 + 10] + wx1 * wy1 * Gp[g00 + 11];
            outp[k * npb] = v * INV_SQRT_D;
        }
    }
}

// ---------------------------------------------------------------------------
extern "C" void kernel_launch(void* const* d_in, const int* in_sizes, int n_in,
                              void* d_out, int out_size, void* d_ws, size_t ws_size,
                              hipStream_t stream) {
    const float* fmap1  = (const float*)d_in[0];
    const float* fmap2  = (const float*)d_in[1];
    const float* coords = (const float*)d_in[2];
    float* out = (float*)d_out;
    float* ws = (float*)d_ws;

    k_prep<<<dim3(400), dim3(256), 0, stream>>>(fmap1, fmap2, coords, ws);
    k_dc<<<dim3(510), dim3(1024), 0, stream>>>(coords, ws, out);
}